// Round 3
// baseline (230.240 us; speedup 1.0000x reference)
//
#include <hip/hip_runtime.h>
#include <math.h>

// out[tok, d] = cos(dot(x[tok,:], W1) + b1) * cos(phi) * W2[d] + b2[d]
// D = 1024, tokens = B*S = 32768. Memory-bound: 134 MB read + 134 MB write.
//
// Structure: one 64-lane wave per token (grid-stride), butterfly shuffle
// reduction (no LDS, no barriers), W1/W2/b2 held in registers across tokens.
// Native clang vector type so __builtin_nontemporal_* accepts the pointer.

#define EMBED_D 1024

typedef float floatx4 __attribute__((ext_vector_type(4)));

__global__ __launch_bounds__(256) void ffq_kernel(
    const float* __restrict__ x,
    const float* __restrict__ W1,
    const float* __restrict__ b1,
    const float* __restrict__ phi,
    const float* __restrict__ W2,
    const float* __restrict__ b2,
    float* __restrict__ out,
    int ntok)
{
    const int lane   = threadIdx.x & 63;
    const int wave   = (int)((blockIdx.x * blockDim.x + threadIdx.x) >> 6);
    const int nwaves = (int)((gridDim.x * blockDim.x) >> 6);

    const float cphi = cosf(phi[0]);
    const float bias = b1[0];

    const floatx4* w14 = (const floatx4*)W1;
    const floatx4* w24 = (const floatx4*)W2;
    const floatx4* b24 = (const floatx4*)b2;

    // Per-lane parameter fragments, loaded once, reused for all tokens.
    floatx4 w1v[4], w2v[4], b2v[4];
    #pragma unroll
    for (int j = 0; j < 4; ++j) {
        w1v[j] = w14[lane + 64 * j];
        w2v[j] = w24[lane + 64 * j];
        b2v[j] = b24[lane + 64 * j];
    }

    for (int tok = wave; tok < ntok; tok += nwaves) {
        const floatx4* x4 = (const floatx4*)(x + (size_t)tok * EMBED_D);
        floatx4 xv[4];
        #pragma unroll
        for (int j = 0; j < 4; ++j)
            xv[j] = __builtin_nontemporal_load(&x4[lane + 64 * j]);

        float v = 0.f;
        #pragma unroll
        for (int j = 0; j < 4; ++j) {
            v = fmaf(xv[j].x, w1v[j].x, v);
            v = fmaf(xv[j].y, w1v[j].y, v);
            v = fmaf(xv[j].z, w1v[j].z, v);
            v = fmaf(xv[j].w, w1v[j].w, v);
        }

        // Butterfly reduction: every lane ends with the full dot product.
        #pragma unroll
        for (int off = 1; off < 64; off <<= 1)
            v += __shfl_xor(v, off, 64);

        const float q = cosf(v + bias) * cphi;

        floatx4* o4 = (floatx4*)(out + (size_t)tok * EMBED_D);
        #pragma unroll
        for (int j = 0; j < 4; ++j) {
            floatx4 o;
            o.x = fmaf(q, w2v[j].x, b2v[j].x);
            o.y = fmaf(q, w2v[j].y, b2v[j].y);
            o.z = fmaf(q, w2v[j].z, b2v[j].z);
            o.w = fmaf(q, w2v[j].w, b2v[j].w);
            __builtin_nontemporal_store(o, &o4[lane + 64 * j]);
        }
    }
}

extern "C" void kernel_launch(void* const* d_in, const int* in_sizes, int n_in,
                              void* d_out, int out_size, void* d_ws, size_t ws_size,
                              hipStream_t stream) {
    const float* x   = (const float*)d_in[0];
    const float* W1  = (const float*)d_in[1];
    const float* b1  = (const float*)d_in[2];
    const float* phi = (const float*)d_in[3];
    const float* W2  = (const float*)d_in[4];
    const float* b2  = (const float*)d_in[5];
    float* out = (float*)d_out;

    const int ntok = in_sizes[0] / EMBED_D;   // B*S = 32768
    // 2048 blocks x 4 waves = 8192 waves -> 4 tokens per wave.
    ffq_kernel<<<2048, 256, 0, stream>>>(x, W1, b1, phi, W2, b2, out, ntok);
}